// Round 1
// baseline (689.842 us; speedup 1.0000x reference)
//
#include <hip/hip_runtime.h>
#include <cstdint>
#include <climits>

#pragma clang fp contract(off)

#define N_PTS 8192
#define B_SZ  4
#define K_NN  20
#define O_CH  64
#define QW    64            // queries per workgroup
#define SSUB  4             // candidate subsets per query
#define JSUB  (N_PTS / SSUB)

// pd = -xx_n - (-2*dot) - xx_m, matching numpy association order, no FMA contraction.
__device__ __forceinline__ float pd_np(float qx, float qy, float qz, float xxn,
                                       float cx, float cy, float cz, float xm) {
  float p0 = qx * cx;
  float p1 = qy * cy;
  float p2 = qz * cz;
  float dot = (p0 + p1) + p2;
  float t = 2.0f * dot - xxn;   // 2*dot exact; single rounding for the subtract
  return t - xm;
}

// gated branchless sorted insert: arr ascending, keeps the 20 LARGEST values.
__device__ __forceinline__ void insert20(float (&arr)[K_NN], float v) {
  float c = v;
#pragma unroll
  for (int u = K_NN - 1; u >= 0; --u) {
    float hi = fmaxf(arr[u], c);
    c = fminf(arr[u], c);
    arr[u] = hi;
  }
}

__global__ __launch_bounds__(256, 2)
void xx_kernel(const float* __restrict__ x, float* __restrict__ xx) {
  int idx = blockIdx.x * 256 + threadIdx.x;   // b*N + n
  if (idx >= B_SZ * N_PTS) return;
  int b = idx >> 13;
  int n = idx & (N_PTS - 1);
  const float* xb = x + (size_t)b * 3 * N_PTS;
  float x0 = xb[n];
  float x1 = xb[n + N_PTS];
  float x2 = xb[n + 2 * N_PTS];
  xx[idx] = (x0 * x0 + x1 * x1) + x2 * x2;    // numpy order, no contraction
}

__global__ __launch_bounds__(256, 2)
void knn_edgeconv_kernel(const float* __restrict__ x,
                         const float* __restrict__ W,
                         const float* __restrict__ bias,
                         const float* __restrict__ xx,
                         float* __restrict__ out) {
  __shared__ float vals[256][21];     // padded stride 21 (bank spread)
  __shared__ float tau_l[QW];
  __shared__ int   cntg[QW];
  __shared__ int   cnte[QW];
  __shared__ int   list_l[QW][29];    // [0..19] strict+final, [20..27] equals, pad

  const int t  = threadIdx.x;
  const int ql = t & 63;
  const int s  = t >> 6;              // subset 0..3
  const int wb = blockIdx.x;          // 0..511
  const int b  = wb >> 7;
  const int n0 = (wb & 127) << 6;
  const int q  = n0 + ql;

  const float* __restrict__ X0  = x + (size_t)b * 3 * N_PTS;
  const float* __restrict__ X1  = X0 + N_PTS;
  const float* __restrict__ X2  = X0 + 2 * N_PTS;
  const float* __restrict__ XXb = xx + b * N_PTS;

  const float qx  = X0[q];
  const float qy  = X1[q];
  const float qz  = X2[q];
  const float xxn = XXb[q];

  float arr[K_NN];
#pragma unroll
  for (int i = 0; i < K_NN; ++i) arr[i] = -__builtin_inff();

  const int j0 = __builtin_amdgcn_readfirstlane(s) * JSUB;
  const int j1 = j0 + JSUB;

  // ---- Phase 1: top-20 pd VALUES over my candidate subset ----
#pragma unroll 4
  for (int j = j0; j < j1; ++j) {
    float pd = pd_np(qx, qy, qz, xxn, X0[j], X1[j], X2[j], XXb[j]);
    if (pd > arr[0]) insert20(arr, pd);
  }

#pragma unroll
  for (int i = 0; i < K_NN; ++i) vals[t][i] = arr[i];
  __syncthreads();

  // ---- Phase 1b: merge 4 subset lists -> exact 20th-largest pd (tau) ----
  if (t < QW) {
#pragma unroll
    for (int l = 1; l < SSUB; ++l) {
      for (int i = 0; i < K_NN; ++i) {
        float v = vals[(l << 6) + t][i];
        if (v > arr[0]) insert20(arr, v);
      }
    }
    tau_l[t] = arr[0];
    cntg[t] = 0;
    cnte[t] = 0;
  }
  __syncthreads();

  // ---- Phase 2: collect indices with pd >= tau ----
  const float tau = tau_l[ql];
#pragma unroll 4
  for (int j = j0; j < j1; ++j) {
    float pd = pd_np(qx, qy, qz, xxn, X0[j], X1[j], X2[j], XXb[j]);
    if (pd >= tau) {
      if (pd > tau) {
        int p = atomicAdd(&cntg[ql], 1);
        if (p < 20) list_l[ql][p] = j;
      } else {
        int p = atomicAdd(&cnte[ql], 1);
        if (p < 8) list_l[ql][27 - p] = j;
      }
    }
  }
  __syncthreads();

  // ---- Phase 2b: resolve ties (top_k keeps LOWEST indices among equals) ----
  if (t < QW) {
    int cs = cntg[t]; if (cs > 19) cs = 19;
    int ce = cnte[t]; if (ce > 8)  ce = 8;
    int need = 20 - cs; if (need > ce) need = ce;
    for (int r = 0; r < need; ++r) {
      int best = INT_MAX, bpos = 0;
      for (int e = 0; e < ce; ++e) {
        int v = list_l[t][27 - e];
        if (v < best) { best = v; bpos = e; }
      }
      list_l[t][cs + r] = best;
      list_l[t][27 - bpos] = INT_MAX;
    }
  }
  __syncthreads();

  // ---- Phase 3: EdgeConv: max_j( W[:,0:3]·(x_m - x_n) ) then +center term, leaky ----
  float acc[16];
#pragma unroll
  for (int oi = 0; oi < 16; ++oi) acc[oi] = -__builtin_inff();
  const int o0 = s * 16;
  const float* __restrict__ Wp = W + o0 * 6;

  for (int nb = 0; nb < K_NN; ++nb) {
    int m = list_l[ql][nb] & (N_PTS - 1);   // mask: memory-safety belt
    float dx = X0[m] - qx;
    float dy = X1[m] - qy;
    float dz = X2[m] - qz;
#pragma unroll
    for (int oi = 0; oi < 16; ++oi) {
      float h = __builtin_fmaf(dz, Wp[oi * 6 + 2],
                __builtin_fmaf(dy, Wp[oi * 6 + 1], dx * Wp[oi * 6 + 0]));
      acc[oi] = fmaxf(acc[oi], h);
    }
  }

#pragma unroll
  for (int oi = 0; oi < 16; ++oi) {
    int o = o0 + oi;
    float base = __builtin_fmaf(qz, Wp[oi * 6 + 5],
                 __builtin_fmaf(qy, Wp[oi * 6 + 4], qx * Wp[oi * 6 + 3])) + bias[o];
    float v = acc[oi] + base;
    v = fmaxf(v, 0.2f * v);                 // leaky_relu (monotone, commutes with max)
    out[((size_t)(b * O_CH + o) << 13) + q] = v;
  }
}

extern "C" void kernel_launch(void* const* d_in, const int* in_sizes, int n_in,
                              void* d_out, int out_size, void* d_ws, size_t ws_size,
                              hipStream_t stream) {
  const float* x    = (const float*)d_in[0];
  const float* W    = (const float*)d_in[1];
  const float* bias = (const float*)d_in[2];
  float* xxbuf = (float*)d_ws;              // B*N floats = 128 KB
  float* out   = (float*)d_out;

  xx_kernel<<<dim3((B_SZ * N_PTS + 255) / 256), dim3(256), 0, stream>>>(x, xxbuf);
  knn_edgeconv_kernel<<<dim3(B_SZ * (N_PTS / QW)), dim3(256), 0, stream>>>(x, W, bias, xxbuf, out);
}

// Round 2
// 493.978 us; speedup vs baseline: 1.3965x; 1.3965x over previous
//
#include <hip/hip_runtime.h>
#include <cstdint>
#include <climits>

#pragma clang fp contract(off)

#define N_PTS 8192
#define B_SZ  4
#define K_NN  20
#define O_CH  64
#define QW    64            // queries per workgroup
#define SSUB  4             // candidate subsets per query (threads per query)
#define JSUB  (N_PTS / SSUB)
#define WARM  128           // warm-up candidates per thread (values-only top-20)
#define CH    128           // chunk size per thread in filtered scan
#define NCH   (JSUB / CH)   // 16 chunks
#define CAP   24            // survivor stack capacity per thread per chunk
#define SPAD  25            // stack row stride in u64 (pad: 200B rows -> <=4-way bank)

typedef unsigned long long u64k;

// pd = -xx_n - (-2*dot) - xx_m, matching numpy association order, no FMA contraction.
__device__ __forceinline__ float pd_np(float qx, float qy, float qz, float xxn,
                                       float cx, float cy, float cz, float xm) {
  float p0 = qx * cx;
  float p1 = qy * cy;
  float p2 = qz * cz;
  float dot = (p0 + p1) + p2;
  float t = 2.0f * dot - xxn;
  return t - xm;
}

// values-only gated branchless sorted insert (ascending; keeps 20 largest)
__device__ __forceinline__ void insert20(float (&arr)[K_NN], float v) {
  float c = v;
#pragma unroll
  for (int u = K_NN - 1; u >= 0; --u) {
    float hi = fmaxf(arr[u], c);
    c = fminf(arr[u], c);
    arr[u] = hi;
  }
}

// packed-key sorted insert: key = (sortable_pd << 13) | (8191 - j)
// unsigned u64 descending order == (pd desc, j asc) == jax.lax.top_k order.
__device__ __forceinline__ void insK(u64k (&a)[K_NN], u64k k) {
  u64k c = k;
#pragma unroll
  for (int u = K_NN - 1; u >= 0; --u) {
    bool g = a[u] > c;
    u64k hi = g ? a[u] : c;
    u64k lo = g ? c : a[u];
    a[u] = hi;
    c = lo;
  }
}

__device__ __forceinline__ u64k packKey(float pd, int j) {
  unsigned s = __float_as_uint(pd);
  unsigned sp = s ^ ((unsigned)((int)s >> 31) | 0x80000000u);
  return ((u64k)sp << 13) | (unsigned)(8191 - j);
}

__device__ __forceinline__ float keyPd(u64k k) {
  unsigned sp = (unsigned)(k >> 13);
  unsigned s = (sp & 0x80000000u) ? (sp & 0x7FFFFFFFu) : ~sp;
  return __uint_as_float(s);
}

__global__ __launch_bounds__(256, 2)
void xx_kernel(const float* __restrict__ x, float* __restrict__ xx) {
  int idx = blockIdx.x * 256 + threadIdx.x;   // b*N + n
  if (idx >= B_SZ * N_PTS) return;
  int b = idx >> 13;
  int n = idx & (N_PTS - 1);
  const float* xb = x + (size_t)b * 3 * N_PTS;
  float x0 = xb[n];
  float x1 = xb[n + N_PTS];
  float x2 = xb[n + 2 * N_PTS];
  xx[idx] = (x0 * x0 + x1 * x1) + x2 * x2;    // numpy order, no contraction
}

__global__ __launch_bounds__(256, 2)
void knn_edgeconv_kernel(const float* __restrict__ x,
                         const float* __restrict__ W,
                         const float* __restrict__ bias,
                         const float* __restrict__ xx,
                         float* __restrict__ out) {
  __shared__ u64k  stk[256][SPAD];    // survivor stacks; aliased as warm-up val buffer
  __shared__ float tau_l[QW];
  __shared__ int   cnt_l[256];
  __shared__ short of_l[256];
  __shared__ int   list_l[QW][21];    // final neighbor indices (padded)

  const int t  = threadIdx.x;
  const int ql = t & 63;
  const int s  = t >> 6;              // subset 0..3 (wave id)
  const int wb = blockIdx.x;          // 0..511
  const int b  = wb >> 7;
  const int n0 = (wb & 127) << 6;
  const int q  = n0 + ql;

  const float* __restrict__ X0  = x + (size_t)b * 3 * N_PTS;
  const float* __restrict__ X1  = X0 + N_PTS;
  const float* __restrict__ X2  = X0 + 2 * N_PTS;
  const float* __restrict__ XXb = xx + b * N_PTS;

  const float qx  = X0[q];
  const float qy  = X1[q];
  const float qz  = X2[q];
  const float xxn = XXb[q];

  const int j0 = __builtin_amdgcn_readfirstlane(s) * JSUB;
  const bool is_owner = (s == (ql & 3));   // 16 owner lanes per wave

  // ---- Warm-up: values-only top-20 of first WARM own candidates ----
  float arr[K_NN];
#pragma unroll
  for (int i = 0; i < K_NN; ++i) arr[i] = -__builtin_inff();
#pragma unroll 4
  for (int jj = 0; jj < WARM; ++jj) {
    int j = j0 + jj;
    float pd = pd_np(qx, qy, qz, xxn, X0[j], X1[j], X2[j], XXb[j]);
    if (pd > arr[0]) insert20(arr, pd);
  }
  {
    float* wv = (float*)(&stk[t][0]);
#pragma unroll
    for (int i = 0; i < K_NN; ++i) wv[i] = arr[i];
  }
  __syncthreads();

  // ---- Owner: merge 4 warm lists -> tau0 (20th-largest of 4*WARM seen) ----
  u64k karr[K_NN];
#pragma unroll
  for (int i = 0; i < K_NN; ++i) karr[i] = 0ULL;
  if (is_owner) {
#pragma unroll
    for (int p = 0; p < SSUB; ++p) {
      if (p == s) continue;
      const float* pv = (const float*)(&stk[(p << 6) + ql][0]);
      for (int i = 0; i < K_NN; ++i) {
        float v = pv[i];
        if (v > arr[0]) insert20(arr, v);
      }
    }
    tau_l[ql] = arr[0];
  }
  __syncthreads();

  // ---- Filtered scan: 16 chunks; push survivor keys; owner drains + tightens tau ----
  for (int c = 0; c < NCH; ++c) {
    const float tau = tau_l[ql];
    int cnt = 0;
    int ofj = -1;
    const int base = j0 + c * CH;
#pragma unroll 4
    for (int jj = 0; jj < CH; ++jj) {
      int j = base + jj;
      float pd = pd_np(qx, qy, qz, xxn, X0[j], X1[j], X2[j], XXb[j]);
      if (pd >= tau) {                      // >= : keep boundary ties
        if (cnt < CAP) {
          stk[t][cnt] = packKey(pd, j);
          ++cnt;
        } else if (ofj < 0) {
          ofj = jj;                         // deterministic overflow fallback
        }
      }
    }
    cnt_l[t] = cnt;
    of_l[t]  = (short)ofj;
    __syncthreads();

    if (is_owner) {
#pragma unroll
      for (int p = 0; p < SSUB; ++p) {
        int pt = (p << 6) + ql;
        int pc = cnt_l[pt];
        for (int i = 0; i < pc; ++i) {
          u64k k = stk[pt][i];
          if (k > karr[0]) insK(karr, k);
        }
      }
#pragma unroll
      for (int p = 0; p < SSUB; ++p) {      // rare: rescan overflowed ranges
        int pt = (p << 6) + ql;
        int oj = of_l[pt];
        if (oj >= 0) {
          int pbase = p * JSUB + c * CH;
          for (int jj = oj; jj < CH; ++jj) {
            int j = pbase + jj;
            float pdv = pd_np(qx, qy, qz, xxn, X0[j], X1[j], X2[j], XXb[j]);
            if (pdv >= tau) {
              u64k k = packKey(pdv, j);
              if (k > karr[0]) insK(karr, k);
            }
          }
        }
      }
      float t20 = keyPd(karr[0]);           // NaN while karr not full -> fmaxf keeps old
      tau_l[ql] = fmaxf(tau, t20);
    }
    __syncthreads();
  }

  // ---- Publish final neighbor indices ----
  if (is_owner) {
#pragma unroll
    for (int i = 0; i < K_NN; ++i)
      list_l[ql][i] = 8191 - (int)(karr[i] & 8191ULL);
  }
  __syncthreads();

  // ---- EdgeConv: max_j( W[:,0:3]·(x_m - x_n) ) + center term, leaky relu ----
  float acc[16];
#pragma unroll
  for (int oi = 0; oi < 16; ++oi) acc[oi] = -__builtin_inff();
  const int o0 = s * 16;
  const float* __restrict__ Wp = W + o0 * 6;

  for (int nb = 0; nb < K_NN; ++nb) {
    int m = list_l[ql][nb] & (N_PTS - 1);   // mask: memory-safety belt
    float dx = X0[m] - qx;
    float dy = X1[m] - qy;
    float dz = X2[m] - qz;
#pragma unroll
    for (int oi = 0; oi < 16; ++oi) {
      float h = __builtin_fmaf(dz, Wp[oi * 6 + 2],
                __builtin_fmaf(dy, Wp[oi * 6 + 1], dx * Wp[oi * 6 + 0]));
      acc[oi] = fmaxf(acc[oi], h);
    }
  }

#pragma unroll
  for (int oi = 0; oi < 16; ++oi) {
    int o = o0 + oi;
    float base = __builtin_fmaf(qz, Wp[oi * 6 + 5],
                 __builtin_fmaf(qy, Wp[oi * 6 + 4], qx * Wp[oi * 6 + 3])) + bias[o];
    float v = acc[oi] + base;
    v = fmaxf(v, 0.2f * v);                 // leaky_relu (monotone, commutes with max)
    out[((size_t)(b * O_CH + o) << 13) + q] = v;
  }
}

extern "C" void kernel_launch(void* const* d_in, const int* in_sizes, int n_in,
                              void* d_out, int out_size, void* d_ws, size_t ws_size,
                              hipStream_t stream) {
  const float* x    = (const float*)d_in[0];
  const float* W    = (const float*)d_in[1];
  const float* bias = (const float*)d_in[2];
  float* xxbuf = (float*)d_ws;              // B*N floats = 128 KB
  float* out   = (float*)d_out;

  xx_kernel<<<dim3((B_SZ * N_PTS + 255) / 256), dim3(256), 0, stream>>>(x, xxbuf);
  knn_edgeconv_kernel<<<dim3(B_SZ * (N_PTS / QW)), dim3(256), 0, stream>>>(x, W, bias, xxbuf, out);
}

// Round 3
// 357.376 us; speedup vs baseline: 1.9303x; 1.3822x over previous
//
#include <hip/hip_runtime.h>
#include <cstdint>
#include <climits>

#pragma clang fp contract(off)

#define N_PTS 8192
#define B_SZ  4
#define K_NN  20
#define O_CH  64
#define QW    64            // queries per workgroup
#define SSUB  8             // candidate subsets per query == waves per block
#define JSUB  (N_PTS / SSUB) // 1024
#define WARM  64            // warm-up candidates per thread (values-only top-20)
#define CAP   16            // survivor stack capacity per thread per chunk
#define SPAD  17            // stack row stride in u64

typedef unsigned long long u64k;

// pd = -xx_n - (-2*dot) - xx_m, matching numpy association order, no FMA contraction.
__device__ __forceinline__ float pd_np(float qx, float qy, float qz, float xxn,
                                       float cx, float cy, float cz, float xm) {
  float p0 = qx * cx;
  float p1 = qy * cy;
  float p2 = qz * cz;
  float dot = (p0 + p1) + p2;
  float t = 2.0f * dot - xxn;
  return t - xm;
}

// values-only gated branchless sorted insert (ascending; keeps 20 largest)
__device__ __forceinline__ void insert20(float (&arr)[K_NN], float v) {
  float c = v;
#pragma unroll
  for (int u = K_NN - 1; u >= 0; --u) {
    float hi = fmaxf(arr[u], c);
    c = fminf(arr[u], c);
    arr[u] = hi;
  }
}

// packed-key sorted insert: key = (sortable_pd << 13) | (8191 - j)
// unsigned u64 descending order == (pd desc, j asc) == jax.lax.top_k order.
__device__ __forceinline__ void insK(u64k (&a)[K_NN], u64k k) {
  u64k c = k;
#pragma unroll
  for (int u = K_NN - 1; u >= 0; --u) {
    bool g = a[u] > c;
    u64k hi = g ? a[u] : c;
    u64k lo = g ? c : a[u];
    a[u] = hi;
    c = lo;
  }
}

__device__ __forceinline__ u64k packKey(float pd, int j) {
  unsigned s = __float_as_uint(pd);
  unsigned sp = s ^ ((unsigned)((int)s >> 31) | 0x80000000u);
  return ((u64k)sp << 13) | (unsigned)(8191 - j);
}

__device__ __forceinline__ float keyPd(u64k k) {
  unsigned sp = (unsigned)(k >> 13);
  unsigned s = (sp & 0x80000000u) ? (sp & 0x7FFFFFFFu) : ~sp;
  return __uint_as_float(s);
}

__global__ __launch_bounds__(256, 2)
void pack_kernel(const float* __restrict__ x, float4* __restrict__ P) {
  int idx = blockIdx.x * 256 + threadIdx.x;   // b*N + n
  if (idx >= B_SZ * N_PTS) return;
  int b = idx >> 13;
  int n = idx & (N_PTS - 1);
  const float* xb = x + (size_t)b * 3 * N_PTS;
  float x0 = xb[n];
  float x1 = xb[n + N_PTS];
  float x2 = xb[n + 2 * N_PTS];
  float xxv = (x0 * x0 + x1 * x1) + x2 * x2;  // numpy order, no contraction
  P[idx] = make_float4(x0, x1, x2, xxv);
}

__global__ __launch_bounds__(512, 4)
void knn_edgeconv_kernel(const float4* __restrict__ P,
                         const float* __restrict__ W,
                         const float* __restrict__ bias,
                         float* __restrict__ out) {
  __shared__ u64k  stk[512 * SPAD];   // survivor stacks; aliased as warm-up val buffer
  __shared__ float tau_l[QW];
  __shared__ int   cnt_l[512];
  __shared__ short of_l[512];
  __shared__ int   list_l[QW][21];    // final neighbor indices (padded)

  const int t  = threadIdx.x;
  const int ql = t & 63;
  const int s  = t >> 6;              // wave id == subset 0..7
  const int wb = blockIdx.x;          // 0..511
  const int b  = wb >> 7;
  const int n0 = (wb & 127) << 6;
  const int q  = n0 + ql;

  const float4* __restrict__ Pb = P + (size_t)b * N_PTS;

  const float4 qc = Pb[q];
  const float qx = qc.x, qy = qc.y, qz = qc.z, xxn = qc.w;

  const int j0 = __builtin_amdgcn_readfirstlane(s) * JSUB;
  const bool is_owner = (t < QW);     // wave 0 lanes own one query each (ql==t)

  // ---- Warm-up: values-only top-20 of first WARM own candidates ----
  float arr[K_NN];
#pragma unroll
  for (int i = 0; i < K_NN; ++i) arr[i] = -__builtin_inff();
#pragma unroll 4
  for (int jj = 0; jj < WARM; ++jj) {
    int j = j0 + jj;
    float4 cd = Pb[j];
    float pd = pd_np(qx, qy, qz, xxn, cd.x, cd.y, cd.z, cd.w);
    if (pd > arr[0]) insert20(arr, pd);
  }
  {
    float* WV = (float*)stk;
#pragma unroll
    for (int i = 0; i < K_NN; ++i) WV[t * 21 + i] = arr[i];
  }
  __syncthreads();

  // ---- Owner: merge 8 warm lists -> tau0 (20th-largest of 8*WARM sampled) ----
  u64k karr[K_NN];
#pragma unroll
  for (int i = 0; i < K_NN; ++i) karr[i] = 0ULL;
  if (is_owner) {
    const float* WV = (const float*)stk;
#pragma unroll
    for (int p = 1; p < SSUB; ++p) {            // own (p==0) list already in arr
      const float* pv = WV + ((p << 6) + t) * 21;
      for (int i = 0; i < K_NN; ++i) {
        float v = pv[i];
        if (v > arr[0]) insert20(arr, v);
      }
    }
    tau_l[t] = arr[0];
  }
  __syncthreads();

  // ---- Filtered scan: 4 geometric chunks; push survivor keys; owner drains ----
  const int CB[5] = {0, 128, 320, 640, 1024};
#pragma unroll
  for (int c = 0; c < 4; ++c) {
    const float tau = tau_l[ql];
    int cnt = 0;
    int ofj = -1;
    const int jb = j0 + CB[c];
    const int je = j0 + CB[c + 1];
#pragma unroll 4
    for (int j = jb; j < je; ++j) {
      float4 cd = Pb[j];
      float pd = pd_np(qx, qy, qz, xxn, cd.x, cd.y, cd.z, cd.w);
      if (pd >= tau) {                      // >= : keep boundary ties
        if (cnt < CAP) {
          stk[t * SPAD + cnt] = packKey(pd, j);
          ++cnt;
        } else if (ofj < 0) {
          ofj = j;                          // deterministic overflow fallback
        }
      }
    }
    cnt_l[t] = cnt;
    of_l[t]  = (short)ofj;
    __syncthreads();

    if (is_owner) {
#pragma unroll
      for (int p = 0; p < SSUB; ++p) {
        int pt = (p << 6) + t;
        int pc = cnt_l[pt];
        const u64k* ps = &stk[pt * SPAD];
        for (int i = 0; i < pc; ++i) {
          u64k k = ps[i];
          if (k > karr[0]) insK(karr, k);
        }
      }
#pragma unroll
      for (int p = 0; p < SSUB; ++p) {      // rare: rescan overflowed ranges
        int pt = (p << 6) + t;
        int oj = of_l[pt];
        if (oj >= 0) {
          int pe = p * JSUB + CB[c + 1];
          for (int j = oj; j < pe; ++j) {
            float4 cd = Pb[j];
            float pdv = pd_np(qx, qy, qz, xxn, cd.x, cd.y, cd.z, cd.w);
            if (pdv >= tau) {
              u64k k = packKey(pdv, j);
              if (k > karr[0]) insK(karr, k);
            }
          }
        }
      }
      float t20 = keyPd(karr[0]);           // NaN while karr not full -> fmaxf keeps old
      tau_l[t] = fmaxf(tau, t20);
    }
    __syncthreads();
  }

  // ---- Publish final neighbor indices ----
  if (is_owner) {
#pragma unroll
    for (int i = 0; i < K_NN; ++i)
      list_l[t][i] = 8191 - (int)(karr[i] & 8191ULL);
  }
  __syncthreads();

  // ---- EdgeConv: max_j( W[:,0:3]·(x_m - x_n) ) + center term, leaky relu ----
  float acc[8];
#pragma unroll
  for (int oi = 0; oi < 8; ++oi) acc[oi] = -__builtin_inff();
  const int o0 = s * 8;
  const float* __restrict__ Wp = W + o0 * 6;

  for (int nb = 0; nb < K_NN; ++nb) {
    int m = list_l[ql][nb] & (N_PTS - 1);   // mask: memory-safety belt
    float4 cm = Pb[m];
    float dx = cm.x - qx;
    float dy = cm.y - qy;
    float dz = cm.z - qz;
#pragma unroll
    for (int oi = 0; oi < 8; ++oi) {
      float h = __builtin_fmaf(dz, Wp[oi * 6 + 2],
                __builtin_fmaf(dy, Wp[oi * 6 + 1], dx * Wp[oi * 6 + 0]));
      acc[oi] = fmaxf(acc[oi], h);
    }
  }

#pragma unroll
  for (int oi = 0; oi < 8; ++oi) {
    int o = o0 + oi;
    float base = __builtin_fmaf(qz, Wp[oi * 6 + 5],
                 __builtin_fmaf(qy, Wp[oi * 6 + 4], qx * Wp[oi * 6 + 3])) + bias[o];
    float v = acc[oi] + base;
    v = fmaxf(v, 0.2f * v);                 // leaky_relu (monotone, commutes with max)
    out[((size_t)(b * O_CH + o) << 13) + q] = v;
  }
}

extern "C" void kernel_launch(void* const* d_in, const int* in_sizes, int n_in,
                              void* d_out, int out_size, void* d_ws, size_t ws_size,
                              hipStream_t stream) {
  const float* x    = (const float*)d_in[0];
  const float* W    = (const float*)d_in[1];
  const float* bias = (const float*)d_in[2];
  float4* P  = (float4*)d_ws;               // B*N float4 = 512 KB
  float* out = (float*)d_out;

  pack_kernel<<<dim3((B_SZ * N_PTS + 255) / 256), dim3(256), 0, stream>>>(x, P);
  knn_edgeconv_kernel<<<dim3(B_SZ * (N_PTS / QW)), dim3(512), 0, stream>>>(P, W, bias, out);
}

// Round 4
// 355.412 us; speedup vs baseline: 1.9410x; 1.0055x over previous
//
#include <hip/hip_runtime.h>
#include <cstdint>
#include <climits>

#pragma clang fp contract(off)

#define N_PTS 8192
#define B_SZ  4
#define K_NN  20
#define O_CH  64
#define QW    64              // queries per block (= lanes per wave)
#define NSW   7               // scanning waves (1..7); wave 0 = drain wave
#define SUBL  1170            // subset length per scan wave (wave 7 gets 1172)
#define WARM  96              // warm-up candidates per scan thread (values-only)
#define CAP   8               // survivor stack capacity per thread per chunk
#define SPAD  9               // stack row stride (u64)
#define NCH   6               // chunks per subset

typedef unsigned long long u64k;

// pd = -xx_n - (-2*dot) - xx_m with numpy rounding order.
// fma(dot,2,-xxn): 2*dot is exact => identical bits to round(2dot - xxn).
__device__ __forceinline__ float pd_np(float qx, float qy, float qz, float xxn,
                                       float cx, float cy, float cz, float xm) {
  float p0 = qx * cx;
  float p1 = qy * cy;
  float p2 = qz * cz;
  float dot = (p0 + p1) + p2;
  float t = __builtin_fmaf(dot, 2.0f, -xxn);
  return t - xm;
}

// values-only gated branchless sorted insert (ascending; keeps 20 largest)
__device__ __forceinline__ void insert20(float (&arr)[K_NN], float v) {
  float c = v;
#pragma unroll
  for (int u = K_NN - 1; u >= 0; --u) {
    float hi = fmaxf(arr[u], c);
    c = fminf(arr[u], c);
    arr[u] = hi;
  }
}

// packed-key sorted insert: key = (sortable_pd << 13) | (8191 - j)
// u64 descending == (pd desc, j asc) == jax.lax.top_k order (set semantics).
__device__ __forceinline__ void insK(u64k (&a)[K_NN], u64k k) {
  u64k c = k;
#pragma unroll
  for (int u = K_NN - 1; u >= 0; --u) {
    bool g = a[u] > c;
    u64k hi = g ? a[u] : c;
    u64k lo = g ? c : a[u];
    a[u] = hi;
    c = lo;
  }
}

__device__ __forceinline__ unsigned sortable32(float pd) {
  unsigned s = __float_as_uint(pd);
  return s ^ ((unsigned)((int)s >> 31) | 0x80000000u);
}

__device__ __forceinline__ u64k packKey(float pd, int j) {
  return ((u64k)sortable32(pd) << 13) | (unsigned)(8191 - j);
}

__device__ __forceinline__ float keyPd(u64k k) {
  unsigned sp = (unsigned)(k >> 13);
  unsigned s = (sp & 0x80000000u) ? (sp & 0x7FFFFFFFu) : ~sp;
  return __uint_as_float(s);
}

__global__ __launch_bounds__(256, 2)
void pack_kernel(const float* __restrict__ x, float4* __restrict__ P) {
  int idx = blockIdx.x * 256 + threadIdx.x;   // b*N + n
  if (idx >= B_SZ * N_PTS) return;
  int b = idx >> 13;
  int n = idx & (N_PTS - 1);
  const float* xb = x + (size_t)b * 3 * N_PTS;
  float x0 = xb[n];
  float x1 = xb[n + N_PTS];
  float x2 = xb[n + 2 * N_PTS];
  float xxv = (x0 * x0 + x1 * x1) + x2 * x2;  // numpy order, no contraction
  P[idx] = make_float4(x0, x1, x2, xxv);
}

__global__ __launch_bounds__(512, 4)
void knn_edgeconv_kernel(const float4* __restrict__ P,
                         const float* __restrict__ W,
                         const float* __restrict__ bias,
                         float* __restrict__ out) {
  __shared__ u64k  stk[2 * NSW * 64 * SPAD];   // double-buffered stacks (also warm scratch)
  __shared__ int   cnt2[2][NSW * 64];
  __shared__ short of2[2][NSW * 64];
  __shared__ float tau_l[QW];
  __shared__ int   list_l[QW][21];

  const int t  = threadIdx.x;
  const int ql = t & 63;
  const int s  = t >> 6;              // wave id: 0 = drain, 1..7 = scan
  const int wb = blockIdx.x;          // 0..511
  const int b  = wb >> 7;
  const int n0 = (wb & 127) << 6;
  const int q  = n0 + ql;

  const float4* __restrict__ Pb = P + (size_t)b * N_PTS;

  const float4 qc = Pb[q];
  const float qx = qc.x, qy = qc.y, qz = qc.z, xxn = qc.w;

  const int sw   = __builtin_amdgcn_readfirstlane(s);
  const int j0   = (sw - 1) * SUBL;            // scan waves only
  const int LEN  = (sw == 7) ? (N_PTS - 6 * SUBL) : SUBL;   // 1172 for wave 7
  const int tid7 = ((sw - 1) << 6) | ql;       // 0..447 for scan waves
  const int CB[NCH + 1] = {0, 96, 192, 320, 512, 800, SUBL};

  // ---- Warm-up (scan waves): values-only top-20 of first WARM own candidates ----
  float arrv[K_NN];
#pragma unroll
  for (int i = 0; i < K_NN; ++i) arrv[i] = -__builtin_inff();
  if (s >= 1) {
    for (int jj = 0; jj < WARM; ++jj) {
      int j = j0 + jj;
      float4 cd = Pb[j];
      float pd = pd_np(qx, qy, qz, xxn, cd.x, cd.y, cd.z, cd.w);
      if (pd > arrv[0]) insert20(arrv, pd);
    }
    float* WV = (float*)stk;
#pragma unroll
    for (int i = 0; i < K_NN; ++i) WV[tid7 * 21 + i] = arrv[i];
  }
  __syncthreads();

  // ---- Drain wave: merge 7 warm lists -> tau0 = exact 20th of 672-sample ----
  u64k karr[K_NN];
#pragma unroll
  for (int i = 0; i < K_NN; ++i) karr[i] = 0ULL;
  if (s == 0) {
    const float* WV = (const float*)stk;
    for (int p = 0; p < NSW; ++p) {
      const float* pv = WV + ((p << 6) + t) * 21;
      for (int i = 0; i < K_NN; ++i) {
        float v = pv[i];
        if (v > arrv[0]) insert20(arrv, v);
      }
    }
    tau_l[t] = arrv[0];
  }
  __syncthreads();

  // ---- Pipelined stages: scan chunk st (waves 1-7) || drain chunk st-1 (wave 0) ----
#define PUSH(pdv, jv)                                          \
  if ((pdv) >= tau) {                                          \
    if (cnt < CAP) { my[cnt] = packKey((pdv), (jv)); ++cnt; }  \
    else if (ofj < 0) ofj = (jv);                              \
  }

  for (int st = 0; st <= NCH; ++st) {
    if (s >= 1 && st < NCH) {
      const int c = st;
      const float tau = tau_l[ql];
      int cnt = 0, ofj = -1;
      const int jb = j0 + CB[c];
      const int je = j0 + ((c == NCH - 1) ? LEN : CB[c + 1]);
      u64k* my = stk + (size_t)(c & 1) * (NSW * 64 * SPAD) + (size_t)tid7 * SPAD;
      int j = jb;
      for (; j + 3 < je; j += 4) {
        float4 d0 = Pb[j];
        float4 d1 = Pb[j + 1];
        float4 d2 = Pb[j + 2];
        float4 d3 = Pb[j + 3];
        float pd0 = pd_np(qx, qy, qz, xxn, d0.x, d0.y, d0.z, d0.w);
        float pd1 = pd_np(qx, qy, qz, xxn, d1.x, d1.y, d1.z, d1.w);
        float pd2 = pd_np(qx, qy, qz, xxn, d2.x, d2.y, d2.z, d2.w);
        float pd3 = pd_np(qx, qy, qz, xxn, d3.x, d3.y, d3.z, d3.w);
        PUSH(pd0, j)
        PUSH(pd1, j + 1)
        PUSH(pd2, j + 2)
        PUSH(pd3, j + 3)
      }
      for (; j < je; ++j) {
        float4 d0 = Pb[j];
        float pd0 = pd_np(qx, qy, qz, xxn, d0.x, d0.y, d0.z, d0.w);
        PUSH(pd0, j)
      }
      cnt2[c & 1][tid7] = cnt;
      of2[c & 1][tid7]  = (short)ofj;
    }
    if (s == 0 && st >= 1) {
      const int c = st - 1;
      const float tauc = tau_l[t];
      const u64k* sb = stk + (size_t)(c & 1) * (NSW * 64 * SPAD);
      for (int p = 0; p < NSW; ++p) {
        const int pt = (p << 6) + t;
        int pc = cnt2[c & 1][pt];
        const u64k* ps = sb + (size_t)pt * SPAD;
        for (int i = 0; i < pc; ++i) {
          u64k k = ps[i];
          if (k > karr[0]) insK(karr, k);
        }
      }
      for (int p = 0; p < NSW; ++p) {        // rare: exact overflow rescan
        const int pt = (p << 6) + t;
        int oj = of2[c & 1][pt];
        if (oj >= 0) {
          int je_abs = p * SUBL +
              ((c == NCH - 1) ? ((p == NSW - 1) ? (N_PTS - 6 * SUBL) : SUBL)
                              : CB[c + 1]);
          for (int j = oj; j < je_abs; ++j) {
            float4 cd = Pb[j];
            float pdv = pd_np(qx, qy, qz, xxn, cd.x, cd.y, cd.z, cd.w);
            if (pdv >= tauc) {
              u64k k = packKey(pdv, j);
              if (k > karr[0]) insK(karr, k);
            }
          }
        }
      }
      float t20 = keyPd(karr[0]);            // NaN while karr not full -> fmaxf keeps old
      tau_l[t] = fmaxf(tauc, t20);
    }
    __syncthreads();
  }
#undef PUSH

  // ---- Publish final neighbor indices ----
  if (s == 0) {
#pragma unroll
    for (int i = 0; i < K_NN; ++i)
      list_l[t][i] = 8191 - (int)(karr[i] & 8191ULL);
  }
  __syncthreads();

  // ---- EdgeConv: max_j( W[:,0:3]·(x_m - x_n) ) + center term, leaky relu ----
  float acc[8];
#pragma unroll
  for (int oi = 0; oi < 8; ++oi) acc[oi] = -__builtin_inff();
  const int o0 = s * 8;
  const float* __restrict__ Wp = W + o0 * 6;

  for (int nb = 0; nb < K_NN; ++nb) {
    int m = list_l[ql][nb] & (N_PTS - 1);   // mask: memory-safety belt
    float4 cm = Pb[m];
    float dx = cm.x - qx;
    float dy = cm.y - qy;
    float dz = cm.z - qz;
#pragma unroll
    for (int oi = 0; oi < 8; ++oi) {
      float h = __builtin_fmaf(dz, Wp[oi * 6 + 2],
                __builtin_fmaf(dy, Wp[oi * 6 + 1], dx * Wp[oi * 6 + 0]));
      acc[oi] = fmaxf(acc[oi], h);
    }
  }

#pragma unroll
  for (int oi = 0; oi < 8; ++oi) {
    int o = o0 + oi;
    float base = __builtin_fmaf(qz, Wp[oi * 6 + 5],
                 __builtin_fmaf(qy, Wp[oi * 6 + 4], qx * Wp[oi * 6 + 3])) + bias[o];
    float v = acc[oi] + base;
    v = fmaxf(v, 0.2f * v);                 // leaky_relu (monotone, commutes with max)
    out[((size_t)(b * O_CH + o) << 13) + q] = v;
  }
}

extern "C" void kernel_launch(void* const* d_in, const int* in_sizes, int n_in,
                              void* d_out, int out_size, void* d_ws, size_t ws_size,
                              hipStream_t stream) {
  const float* x    = (const float*)d_in[0];
  const float* W    = (const float*)d_in[1];
  const float* bias = (const float*)d_in[2];
  float4* P  = (float4*)d_ws;               // B*N float4 = 512 KB
  float* out = (float*)d_out;

  pack_kernel<<<dim3((B_SZ * N_PTS + 255) / 256), dim3(256), 0, stream>>>(x, P);
  knn_edgeconv_kernel<<<dim3(B_SZ * (N_PTS / QW)), dim3(512), 0, stream>>>(P, W, bias, out);
}